// Round 2
// baseline (550.527 us; speedup 1.0000x reference)
//
#include <hip/hip_runtime.h>
#include <hip/hip_bf16.h>
#include <stdint.h>

// Complex-valued MHA: B=2, S=2048, D=512, H=8, DK=64
#define Bb 2
#define Ss 2048
#define Dd 512
#define Hh 8
#define DKk 64

// sizes (elements)
#define NROW 4096            // B*S
#define MAT_E 2097152        // B*S*D
#define W_E 262144           // D*D

typedef __attribute__((ext_vector_type(8))) short short8;
typedef __attribute__((ext_vector_type(4))) float f32x4;

__device__ __forceinline__ unsigned short f2bf(float f) {
  union { float f; uint32_t u; } v; v.f = f;
  uint32_t u = v.u;
  uint32_t r = u + 0x7FFFu + ((u >> 16) & 1u);   // round-to-nearest-even
  return (unsigned short)(r >> 16);
}

// ---------------- 1a. convert activations fp32 -> bf16 ----------------
__global__ __launch_bounds__(256) void ck_cvt_in(
    const float* __restrict__ a0, const float* __restrict__ a1,
    const float* __restrict__ a2, const float* __restrict__ a3,
    const float* __restrict__ a4, const float* __restrict__ a5,
    unsigned short* __restrict__ out)
{
  int z = blockIdx.y;
  const float* src = z==0?a0: z==1?a1: z==2?a2: z==3?a3: z==4?a4: a5;
  unsigned short* dst = out + (size_t)z * MAT_E;
  int i = blockIdx.x * 256 + threadIdx.x;          // 2048*256*4 = MAT_E
  float4 v = ((const float4*)src)[i];
  unsigned short o[4] = {f2bf(v.x), f2bf(v.y), f2bf(v.z), f2bf(v.w)};
  *((uint2*)(dst + (size_t)i * 4)) = *((uint2*)o);
}

// ---------------- 1b. convert + transpose weights: Wt[d][k] = w[k][d] ----
__global__ __launch_bounds__(256) void ck_cvt_wt(
    const float* __restrict__ w0, const float* __restrict__ w1,
    const float* __restrict__ w2, const float* __restrict__ w3,
    unsigned short* __restrict__ out)
{
  int z = blockIdx.y;
  const float* w = z==0?w0: z==1?w1: z==2?w2: w3;
  unsigned short* wt = out + (size_t)z * W_E;
  int t = blockIdx.x * 256 + threadIdx.x;          // t = d*512 + k
  int d = t >> 9, k = t & 511;
  wt[t] = f2bf(w[k * 512 + d]);                    // strided read (L2-cached), coalesced write
}

// ---------------- 2. projection GEMM ----------------
// z: 0=qr(wq) 1=kr(wk) 2=vr(wv,transposed out) 3=qp(wq) 4=kp(wk) 5=vp(wv,transposed)
// Note on XCD locality: linear block id = x + 64*y + 512*z; blocks sharing an
// A-panel (same x,z; varying y) differ by 64 ≡ 0 (mod 8) -> same XCD already.
__device__ const size_t PROJ_OFF[6] = {0, 2097152, 8388608, 4194304, 6291456, 10485760};

__global__ __launch_bounds__(256) void ck_proj_gemm(
    const unsigned short* __restrict__ xb,   // 6 x [4096,512] bf16
    const unsigned short* __restrict__ wt,   // 4 x [512,512] bf16 (transposed)
    unsigned short* __restrict__ proj)
{
  int z = blockIdx.z;
  int wsel = z % 3;
  const unsigned short* A = xb + (size_t)z * MAT_E;
  const unsigned short* W = wt + (size_t)wsel * W_E;

  int wave = threadIdx.x >> 6, lane = threadIdx.x & 63;
  int lo = lane & 15, hi = lane >> 4;
  int m0 = blockIdx.x * 64 + wave * 16;
  int n0 = blockIdx.y * 64;

  f32x4 acc[4];
  #pragma unroll
  for (int t = 0; t < 4; ++t) acc[t] = (f32x4){0.f, 0.f, 0.f, 0.f};

  for (int k0 = 0; k0 < 512; k0 += 32) {
    // A-frag: row = lane&15, k = 8*(lane>>4)+e (contiguous 16B)
    short8 a = *(const short8*)(A + (size_t)(m0 + lo) * 512 + k0 + 8 * hi);
    #pragma unroll
    for (int t = 0; t < 4; ++t) {
      short8 b = *(const short8*)(W + (size_t)(n0 + 16 * t + lo) * 512 + k0 + 8 * hi);
      acc[t] = __builtin_amdgcn_mfma_f32_16x16x32_bf16(a, b, acc[t], 0, 0, 0);
    }
  }

  // epilogue through LDS so global writes are 16B coalesced
  __shared__ __align__(16) unsigned short tile[64 * 64];
  bool isV = (z == 2 || z == 5);
  #pragma unroll
  for (int t = 0; t < 4; ++t) {
    #pragma unroll
    for (int r = 0; r < 4; ++r) {
      int row = wave * 16 + 4 * hi + r;     // s_local  (D-layout: row=(lane>>4)*4+reg, col=lane&15)
      int col = 16 * t + lo;                // dk
      unsigned short val = f2bf(acc[t][r]);
      if (isV) tile[col * 64 + row] = val;  // store transposed: [dk][s_local]
      else     tile[row * 64 + col] = val;  // [s_local][dk]
    }
  }
  __syncthreads();

  int gm0 = blockIdx.x * 64;
  int b = gm0 >> 11;
  int s0 = gm0 & 2047;
  int h = blockIdx.y;                        // 64 cols per head -> blockIdx.y == h
  unsigned short* dst = proj + PROJ_OFF[z];
  #pragma unroll
  for (int c = threadIdx.x; c < 512; c += 256) {
    int row = c >> 3, chunk = c & 7;
    uint4 data = *((uint4*)(tile + row * 64 + chunk * 8));
    size_t off;
    if (isV)  // Vt[b,h,dk,s]: row = dk
      off = ((size_t)(b * Hh + h) * 64 + row) * 2048 + s0 + chunk * 8;
    else      // [b,h,s,dk]: row = s_local
      off = ((size_t)(b * Hh + h) * 2048 + s0 + row) * 64 + chunk * 8;
    *((uint4*)(dst + off)) = data;
  }
}

// ---------------- 3. fused complex flash attention ----------------
// 1D grid, XCD-aware swizzle (T1): 512 blocks, 512%8==0 -> bijective remap.
// Each XCD gets 64 consecutive logical blocks = 2 complete (b,h) groups, so
// the 1MB K/V panel of each (b,h) is fetched into ONE XCD L2, not all 8.
__global__ __launch_bounds__(256) void ck_attn(
    const unsigned short* __restrict__ proj,
    const int* __restrict__ mask,
    unsigned short* __restrict__ xout)       // xr @0, xp @MAT_E  [B,S,D] bf16
{
  const unsigned short* qr  = proj;
  const unsigned short* kr  = proj + 2097152;
  const unsigned short* qp  = proj + 4194304;
  const unsigned short* kp  = proj + 6291456;
  const unsigned short* vrt = proj + 8388608;   // [B,H,DK,S]
  const unsigned short* vpt = proj + 10485760;

  int bid = blockIdx.x;
  int swz = (bid & 7) * 64 + (bid >> 3);     // bijective XCD swizzle
  int qt = swz & 31, h = (swz >> 5) & 7, b = swz >> 8;

  int wave = threadIdx.x >> 6, lane = threadIdx.x & 63;
  int lo = lane & 15, hi = lane >> 4;
  int bh = b * Hh + h;
  size_t base = (size_t)bh * Ss * DKk;
  const unsigned short* Qr = qr + base;
  const unsigned short* Kr = kr + base;
  const unsigned short* Qp = qp + base;
  const unsigned short* Kp = kp + base;
  const unsigned short* Vr = vrt + base;
  const unsigned short* Vp = vpt + base;

  int q0 = qt * 64 + wave * 16;              // this wave's 16 q-rows

  // Q fragments, held for the whole kernel. fqpn = -qp (bf16 sign flip) for the
  // attn_real = qr*kr - qp*kp term (MFMA only accumulates).
  short8 fqr[2], fqp[2], fqpn[2];
  #pragma unroll
  for (int hf = 0; hf < 2; ++hf) {
    fqr[hf] = *(const short8*)(Qr + (size_t)(q0 + lo) * 64 + 32 * hf + 8 * hi);
    short8 p = *(const short8*)(Qp + (size_t)(q0 + lo) * 64 + 32 * hf + 8 * hi);
    fqp[hf] = p;
    union { short8 s; uint32_t u[4]; } pu; pu.s = p;
    #pragma unroll
    for (int i = 0; i < 4; ++i) pu.u[i] ^= 0x80008000u;
    fqpn[hf] = pu.s;
  }

  f32x4 o_r[4], o_p[4];
  float m_run[4], l_run[4];
  #pragma unroll
  for (int n = 0; n < 4; ++n) { o_r[n] = (f32x4){0,0,0,0}; o_p[n] = (f32x4){0,0,0,0}; }
  #pragma unroll
  for (int r = 0; r < 4; ++r) { m_run[r] = -1e30f; l_run[r] = 0.f; }

  __shared__ __align__(16) unsigned short plds[4 * 1024];  // 2KB per wave
  char* pbase = (char*)plds + wave * 2048;
  const float inv_scale = 0.08838834764831845f;            // 1/sqrt(2*DK)

  for (int k0 = 0; k0 < Ss; k0 += 64) {
    // ---- scores: 4 col-tiles of 16, complex re/ph via 8 MFMAs each ----
    f32x4 sre[4], sph[4];
    #pragma unroll
    for (int t = 0; t < 4; ++t) {
      const unsigned short* krow = Kr + (size_t)(k0 + 16 * t + lo) * 64;
      const unsigned short* prow = Kp + (size_t)(k0 + 16 * t + lo) * 64;
      short8 bkr0 = *(const short8*)(krow + 8 * hi);
      short8 bkr1 = *(const short8*)(krow + 32 + 8 * hi);
      short8 bkp0 = *(const short8*)(prow + 8 * hi);
      short8 bkp1 = *(const short8*)(prow + 32 + 8 * hi);
      f32x4 re = (f32x4){0,0,0,0};
      re = __builtin_amdgcn_mfma_f32_16x16x32_bf16(fqr[0],  bkr0, re, 0,0,0);
      re = __builtin_amdgcn_mfma_f32_16x16x32_bf16(fqr[1],  bkr1, re, 0,0,0);
      re = __builtin_amdgcn_mfma_f32_16x16x32_bf16(fqpn[0], bkp0, re, 0,0,0);
      re = __builtin_amdgcn_mfma_f32_16x16x32_bf16(fqpn[1], bkp1, re, 0,0,0);
      f32x4 ph = (f32x4){0,0,0,0};
      ph = __builtin_amdgcn_mfma_f32_16x16x32_bf16(fqr[0],  bkp0, ph, 0,0,0);
      ph = __builtin_amdgcn_mfma_f32_16x16x32_bf16(fqr[1],  bkp1, ph, 0,0,0);
      ph = __builtin_amdgcn_mfma_f32_16x16x32_bf16(fqp[0],  bkr0, ph, 0,0,0);
      ph = __builtin_amdgcn_mfma_f32_16x16x32_bf16(fqp[1],  bkr1, ph, 0,0,0);
      sre[t] = re; sph[t] = ph;
    }

    // ---- magnitude + mask + online softmax (rows live in 16-lane groups) ----
    float pvals[4][4];
    float rmax[4];
    #pragma unroll
    for (int r = 0; r < 4; ++r) rmax[r] = -1e30f;
    #pragma unroll
    for (int t = 0; t < 4; ++t) {
      #pragma unroll
      for (int r = 0; r < 4; ++r) {
        float re = sre[t][r], ph = sph[t][r];
        float v = sqrtf(re * re + ph * ph) * inv_scale;
        int q = q0 + 4 * hi + r;
        int mv = mask[((size_t)b * Ss + q) * Ss + k0 + 16 * t + lo];
        v = (mv == 0) ? -1e9f : v;
        pvals[t][r] = v;
        rmax[r] = fmaxf(rmax[r], v);
      }
    }
    #pragma unroll
    for (int r = 0; r < 4; ++r) {
      float v = rmax[r];
      v = fmaxf(v, __shfl_xor(v, 1));
      v = fmaxf(v, __shfl_xor(v, 2));
      v = fmaxf(v, __shfl_xor(v, 4));
      v = fmaxf(v, __shfl_xor(v, 8));
      rmax[r] = v;
    }
    #pragma unroll
    for (int r = 0; r < 4; ++r) {
      float mnew = fmaxf(m_run[r], rmax[r]);
      float alpha = __expf(m_run[r] - mnew);
      m_run[r] = mnew;
      float rs = 0.f;
      #pragma unroll
      for (int t = 0; t < 4; ++t) {
        float p = __expf(pvals[t][r] - mnew);
        pvals[t][r] = p;
        rs += p;
      }
      rs += __shfl_xor(rs, 1);
      rs += __shfl_xor(rs, 2);
      rs += __shfl_xor(rs, 4);
      rs += __shfl_xor(rs, 8);
      l_run[r] = l_run[r] * alpha + rs;
      #pragma unroll
      for (int n = 0; n < 4; ++n) { o_r[n][r] *= alpha; o_p[n][r] *= alpha; }
    }

    // ---- P -> bf16 -> LDS, XOR-swizzled (G4: stride-128B rows = 32-way conflict) ----
    #pragma unroll
    for (int t = 0; t < 4; ++t) {
      #pragma unroll
      for (int r = 0; r < 4; ++r) {
        int row = 4 * hi + r;
        int off = row * 128 + ((((16 * t + lo) * 2) ^ ((row & 7) << 4)));
        *(unsigned short*)(pbase + off) = f2bf(pvals[t][r]);
      }
    }
    __syncthreads();

    // ---- PV: A = P from LDS (row=q=lane&15, k'=8*hi+e), B = Vt rows (contiguous) ----
    short8 pa[2];
    #pragma unroll
    for (int hf = 0; hf < 2; ++hf) {
      int off = lo * 128 + (((hf * 64 + hi * 16)) ^ ((lo & 7) << 4));
      pa[hf] = *(const short8*)(pbase + off);
    }
    #pragma unroll
    for (int n = 0; n < 4; ++n) {
      const unsigned short* vr_row = Vr + (size_t)(16 * n + lo) * 2048 + k0;
      const unsigned short* vp_row = Vp + (size_t)(16 * n + lo) * 2048 + k0;
      short8 bvr0 = *(const short8*)(vr_row + 8 * hi);
      short8 bvr1 = *(const short8*)(vr_row + 32 + 8 * hi);
      short8 bvp0 = *(const short8*)(vp_row + 8 * hi);
      short8 bvp1 = *(const short8*)(vp_row + 32 + 8 * hi);
      o_r[n] = __builtin_amdgcn_mfma_f32_16x16x32_bf16(pa[0], bvr0, o_r[n], 0,0,0);
      o_r[n] = __builtin_amdgcn_mfma_f32_16x16x32_bf16(pa[1], bvr1, o_r[n], 0,0,0);
      o_p[n] = __builtin_amdgcn_mfma_f32_16x16x32_bf16(pa[0], bvp0, o_p[n], 0,0,0);
      o_p[n] = __builtin_amdgcn_mfma_f32_16x16x32_bf16(pa[1], bvp1, o_p[n], 0,0,0);
    }
    __syncthreads();
  }

  // ---- epilogue: normalize, write xr/xp bf16 [B,S,D] ----
  float invl[4];
  #pragma unroll
  for (int r = 0; r < 4; ++r) invl[r] = 1.f / l_run[r];
  #pragma unroll
  for (int n = 0; n < 4; ++n) {
    #pragma unroll
    for (int r = 0; r < 4; ++r) {
      int q = q0 + 4 * hi + r;
      size_t off = (size_t)(b * Ss + q) * Dd + h * 64 + 16 * n + lo;
      xout[off]          = f2bf(o_r[n][r] * invl[r]);
      xout[MAT_E + off]  = f2bf(o_p[n][r] * invl[r]);
    }
  }
}

// ---------------- 4. output projection -> fp32 d_out ----------------
__global__ __launch_bounds__(256) void ck_out_gemm(
    const unsigned short* __restrict__ x,    // xr@0, xp@MAT_E bf16 [4096,512]
    const unsigned short* __restrict__ wot,  // w_o transposed bf16 [512,512]
    float* __restrict__ out)                 // z=0 -> first half, z=1 -> second
{
  int z = blockIdx.z;
  const unsigned short* A = x + (size_t)z * MAT_E;
  float* O = out + (size_t)z * MAT_E;

  int wave = threadIdx.x >> 6, lane = threadIdx.x & 63;
  int lo = lane & 15, hi = lane >> 4;
  int m0 = blockIdx.x * 64 + wave * 16;
  int n0 = blockIdx.y * 64;

  f32x4 acc[4];
  #pragma unroll
  for (int t = 0; t < 4; ++t) acc[t] = (f32x4){0.f, 0.f, 0.f, 0.f};

  for (int k0 = 0; k0 < 512; k0 += 32) {
    short8 a = *(const short8*)(A + (size_t)(m0 + lo) * 512 + k0 + 8 * hi);
    #pragma unroll
    for (int t = 0; t < 4; ++t) {
      short8 b = *(const short8*)(wot + (size_t)(n0 + 16 * t + lo) * 512 + k0 + 8 * hi);
      acc[t] = __builtin_amdgcn_mfma_f32_16x16x32_bf16(a, b, acc[t], 0, 0, 0);
    }
  }
  #pragma unroll
  for (int t = 0; t < 4; ++t) {
    #pragma unroll
    for (int r = 0; r < 4; ++r) {
      int m = m0 + 4 * hi + r;
      int n = n0 + 16 * t + lo;
      O[(size_t)m * 512 + n] = acc[t][r];
    }
  }
}

// ---------------- launch ----------------
extern "C" void kernel_launch(void* const* d_in, const int* in_sizes, int n_in,
                              void* d_out, int out_size, void* d_ws, size_t ws_size,
                              hipStream_t stream) {
  const float* q_real  = (const float*)d_in[0];
  const float* k_real  = (const float*)d_in[1];
  const float* v_real  = (const float*)d_in[2];
  const float* q_phase = (const float*)d_in[3];
  const float* k_phase = (const float*)d_in[4];
  const float* v_phase = (const float*)d_in[5];
  const float* w_q     = (const float*)d_in[6];
  const float* w_k     = (const float*)d_in[7];
  const float* w_v     = (const float*)d_in[8];
  const float* w_o     = (const float*)d_in[9];
  const int*   mask    = (const int*)d_in[10];
  float* out = (float*)d_out;

  unsigned short* ws   = (unsigned short*)d_ws;
  unsigned short* XB   = ws;                            // 6 * MAT_E bf16
  unsigned short* WT   = ws + 6 * (size_t)MAT_E;        // 4 * W_E
  unsigned short* PROJ = WT + 4 * (size_t)W_E;          // 6 * MAT_E
  unsigned short* XOUT = PROJ + 6 * (size_t)MAT_E;      // 2 * MAT_E
  // total ~58 MB of workspace

  ck_cvt_in  <<<dim3(2048, 6), 256, 0, stream>>>(q_real, k_real, v_real,
                                                 q_phase, k_phase, v_phase, XB);
  ck_cvt_wt  <<<dim3(1024, 4), 256, 0, stream>>>(w_q, w_k, w_v, w_o, WT);
  ck_proj_gemm<<<dim3(64, 8, 6), 256, 0, stream>>>(XB, WT, PROJ);
  ck_attn    <<<dim3(512), 256, 0, stream>>>(PROJ, mask, XOUT);
  ck_out_gemm<<<dim3(64, 8, 2), 256, 0, stream>>>(XOUT, WT + 3 * (size_t)W_E, out);
}

// Round 3
// 532.153 us; speedup vs baseline: 1.0345x; 1.0345x over previous
//
#include <hip/hip_runtime.h>
#include <hip/hip_bf16.h>
#include <stdint.h>

// Complex-valued MHA: B=2, S=2048, D=512, H=8, DK=64
#define Bb 2
#define Ss 2048
#define Dd 512
#define Hh 8
#define DKk 64

// sizes (elements)
#define NROW 4096            // B*S
#define MAT_E 2097152        // B*S*D
#define W_E 262144           // D*D

typedef __attribute__((ext_vector_type(8))) short short8;
typedef __attribute__((ext_vector_type(4))) float f32x4;

__device__ __forceinline__ unsigned short f2bf(float f) {
  union { float f; uint32_t u; } v; v.f = f;
  uint32_t u = v.u;
  uint32_t r = u + 0x7FFFu + ((u >> 16) & 1u);   // round-to-nearest-even
  return (unsigned short)(r >> 16);
}

// ---------------- 1a. convert activations fp32 -> bf16 ----------------
__global__ __launch_bounds__(256) void ck_cvt_in(
    const float* __restrict__ a0, const float* __restrict__ a1,
    const float* __restrict__ a2, const float* __restrict__ a3,
    const float* __restrict__ a4, const float* __restrict__ a5,
    unsigned short* __restrict__ out)
{
  int z = blockIdx.y;
  const float* src = z==0?a0: z==1?a1: z==2?a2: z==3?a3: z==4?a4: a5;
  unsigned short* dst = out + (size_t)z * MAT_E;
  int i = blockIdx.x * 256 + threadIdx.x;          // 2048*256*4 = MAT_E
  float4 v = ((const float4*)src)[i];
  unsigned short o[4] = {f2bf(v.x), f2bf(v.y), f2bf(v.z), f2bf(v.w)};
  *((uint2*)(dst + (size_t)i * 4)) = *((uint2*)o);
}

// ---------------- 1b. convert + transpose weights: Wt[d][k] = w[k][d] ----
__global__ __launch_bounds__(256) void ck_cvt_wt(
    const float* __restrict__ w0, const float* __restrict__ w1,
    const float* __restrict__ w2, const float* __restrict__ w3,
    unsigned short* __restrict__ out)
{
  int z = blockIdx.y;
  const float* w = z==0?w0: z==1?w1: z==2?w2: w3;
  unsigned short* wt = out + (size_t)z * W_E;
  int t = blockIdx.x * 256 + threadIdx.x;          // t = d*512 + k
  int d = t >> 9, k = t & 511;
  wt[t] = f2bf(w[k * 512 + d]);                    // strided read (L2-cached), coalesced write
}

// ---------------- 1c. pack mask int32 -> 64-bit words (1 bit per k) -------
// mb[b][q][w] bit j = (mask[b][q][64w+j] != 0). 1 MB total, aliases dead XB.
__global__ __launch_bounds__(256) void ck_mask_pack(
    const int* __restrict__ mask, unsigned long long* __restrict__ mb)
{
  size_t i = (size_t)blockIdx.x * 256 + threadIdx.x;   // B*S*S threads
  int v = mask[i];
  unsigned long long bits = __ballot(v != 0);
  if ((threadIdx.x & 63) == 0) mb[i >> 6] = bits;
}

// ---------------- 2. projection GEMM ----------------
// z: 0=qr(wq) 1=kr(wk) 2=vr(wv,transposed out) 3=qp(wq) 4=kp(wk) 5=vp(wv,transposed)
// XCD note: linear id = x + 64*y + 512*z; same-A blocks differ by 64 ≡ 0 mod 8 -> same XCD.
__device__ const size_t PROJ_OFF[6] = {0, 2097152, 8388608, 4194304, 6291456, 10485760};

__global__ __launch_bounds__(256) void ck_proj_gemm(
    const unsigned short* __restrict__ xb,   // 6 x [4096,512] bf16
    const unsigned short* __restrict__ wt,   // 4 x [512,512] bf16 (transposed)
    unsigned short* __restrict__ proj)
{
  int z = blockIdx.z;
  int wsel = z % 3;
  const unsigned short* A = xb + (size_t)z * MAT_E;
  const unsigned short* W = wt + (size_t)wsel * W_E;

  int wave = threadIdx.x >> 6, lane = threadIdx.x & 63;
  int lo = lane & 15, hi = lane >> 4;
  int m0 = blockIdx.x * 64 + wave * 16;
  int n0 = blockIdx.y * 64;

  f32x4 acc[4];
  #pragma unroll
  for (int t = 0; t < 4; ++t) acc[t] = (f32x4){0.f, 0.f, 0.f, 0.f};

  for (int k0 = 0; k0 < 512; k0 += 32) {
    // A-frag: row = lane&15, k = 8*(lane>>4)+e (contiguous 16B)
    short8 a = *(const short8*)(A + (size_t)(m0 + lo) * 512 + k0 + 8 * hi);
    #pragma unroll
    for (int t = 0; t < 4; ++t) {
      short8 b = *(const short8*)(W + (size_t)(n0 + 16 * t + lo) * 512 + k0 + 8 * hi);
      acc[t] = __builtin_amdgcn_mfma_f32_16x16x32_bf16(a, b, acc[t], 0, 0, 0);
    }
  }

  // epilogue through LDS so global writes are 16B coalesced
  __shared__ __align__(16) unsigned short tile[64 * 64];
  bool isV = (z == 2 || z == 5);
  #pragma unroll
  for (int t = 0; t < 4; ++t) {
    #pragma unroll
    for (int r = 0; r < 4; ++r) {
      int row = wave * 16 + 4 * hi + r;     // s_local  (D-layout: row=(lane>>4)*4+reg, col=lane&15)
      int col = 16 * t + lo;                // dk
      unsigned short val = f2bf(acc[t][r]);
      if (isV) tile[col * 64 + row] = val;  // store transposed: [dk][s_local]
      else     tile[row * 64 + col] = val;  // [s_local][dk]
    }
  }
  __syncthreads();

  int gm0 = blockIdx.x * 64;
  int b = gm0 >> 11;
  int s0 = gm0 & 2047;
  int h = blockIdx.y;                        // 64 cols per head -> blockIdx.y == h
  unsigned short* dst = proj + PROJ_OFF[z];
  #pragma unroll
  for (int c = threadIdx.x; c < 512; c += 256) {
    int row = c >> 3, chunk = c & 7;
    uint4 data = *((uint4*)(tile + row * 64 + chunk * 8));
    size_t off;
    if (isV)  // Vt[b,h,dk,s]: row = dk
      off = ((size_t)(b * Hh + h) * 64 + row) * 2048 + s0 + chunk * 8;
    else      // [b,h,s,dk]: row = s_local
      off = ((size_t)(b * Hh + h) * 2048 + s0 + row) * 64 + chunk * 8;
    *((uint4*)(dst + off)) = data;
  }
}

// ---------------- 3. fused complex flash attention ----------------
// 1D grid, XCD-aware swizzle (T1): 512 blocks, 512%8==0 -> bijective remap.
// NO intra-loop barriers: the P-LDS slice is wave-private, so waves run free
// and overlap MFMA/VALU/VMEM across the CU (m114 co-scheduling).
__global__ __launch_bounds__(256) void ck_attn(
    const unsigned short* __restrict__ proj,
    const unsigned long long* __restrict__ mb,   // packed mask [B,S,32]
    unsigned short* __restrict__ xout)       // xr @0, xp @MAT_E  [B,S,D] bf16
{
  const unsigned short* qr  = proj;
  const unsigned short* kr  = proj + 2097152;
  const unsigned short* qp  = proj + 4194304;
  const unsigned short* kp  = proj + 6291456;
  const unsigned short* vrt = proj + 8388608;   // [B,H,DK,S]
  const unsigned short* vpt = proj + 10485760;

  int bid = blockIdx.x;
  int swz = (bid & 7) * 64 + (bid >> 3);     // bijective XCD swizzle
  int qt = swz & 31, h = (swz >> 5) & 7, b = swz >> 8;

  int wave = threadIdx.x >> 6, lane = threadIdx.x & 63;
  int lo = lane & 15, hi = lane >> 4;
  int bh = b * Hh + h;
  size_t base = (size_t)bh * Ss * DKk;
  const unsigned short* Qr = qr + base;
  const unsigned short* Kr = kr + base;
  const unsigned short* Qp = qp + base;
  const unsigned short* Kp = kp + base;
  const unsigned short* Vr = vrt + base;
  const unsigned short* Vp = vpt + base;

  int q0 = qt * 64 + wave * 16;              // this wave's 16 q-rows
  const unsigned long long* MBq = mb + ((size_t)b * Ss + q0) * 32;

  // Q fragments, held for the whole kernel. fqpn = -qp (bf16 sign flip) for the
  // attn_real = qr*kr - qp*kp term (MFMA only accumulates).
  short8 fqr[2], fqp[2], fqpn[2];
  #pragma unroll
  for (int hf = 0; hf < 2; ++hf) {
    fqr[hf] = *(const short8*)(Qr + (size_t)(q0 + lo) * 64 + 32 * hf + 8 * hi);
    short8 p = *(const short8*)(Qp + (size_t)(q0 + lo) * 64 + 32 * hf + 8 * hi);
    fqp[hf] = p;
    union { short8 s; uint32_t u[4]; } pu; pu.s = p;
    #pragma unroll
    for (int i = 0; i < 4; ++i) pu.u[i] ^= 0x80008000u;
    fqpn[hf] = pu.s;
  }

  f32x4 o_r[4], o_p[4];
  float m_run[4], l_run[4];
  #pragma unroll
  for (int n = 0; n < 4; ++n) { o_r[n] = (f32x4){0,0,0,0}; o_p[n] = (f32x4){0,0,0,0}; }
  #pragma unroll
  for (int r = 0; r < 4; ++r) { m_run[r] = -1e30f; l_run[r] = 0.f; }

  __shared__ __align__(16) unsigned short plds[4 * 1024];  // 2KB per wave, wave-private
  char* pbase = (char*)plds + wave * 2048;
  const float inv_scale = 0.08838834764831845f;            // 1/sqrt(2*DK)

  for (int k0 = 0; k0 < Ss; k0 += 64) {
    // ---- packed mask words for this 64-col tile (one u64 per q-row) ----
    int wq = k0 >> 6;
    unsigned long long mrow[4];
    #pragma unroll
    for (int r = 0; r < 4; ++r) mrow[r] = MBq[(size_t)(4 * hi + r) * 32 + wq];
    unsigned long long andw = mrow[0] & mrow[1] & mrow[2] & mrow[3];
    bool need_mask = !__all((int)(andw == 0xFFFFFFFFFFFFFFFFull));

    // ---- scores: 4 col-tiles of 16, complex re/ph via 8 MFMAs each ----
    f32x4 sre[4], sph[4];
    #pragma unroll
    for (int t = 0; t < 4; ++t) {
      const unsigned short* krow = Kr + (size_t)(k0 + 16 * t + lo) * 64;
      const unsigned short* prow = Kp + (size_t)(k0 + 16 * t + lo) * 64;
      short8 bkr0 = *(const short8*)(krow + 8 * hi);
      short8 bkr1 = *(const short8*)(krow + 32 + 8 * hi);
      short8 bkp0 = *(const short8*)(prow + 8 * hi);
      short8 bkp1 = *(const short8*)(prow + 32 + 8 * hi);
      f32x4 re = (f32x4){0,0,0,0};
      re = __builtin_amdgcn_mfma_f32_16x16x32_bf16(fqr[0],  bkr0, re, 0,0,0);
      re = __builtin_amdgcn_mfma_f32_16x16x32_bf16(fqr[1],  bkr1, re, 0,0,0);
      re = __builtin_amdgcn_mfma_f32_16x16x32_bf16(fqpn[0], bkp0, re, 0,0,0);
      re = __builtin_amdgcn_mfma_f32_16x16x32_bf16(fqpn[1], bkp1, re, 0,0,0);
      f32x4 ph = (f32x4){0,0,0,0};
      ph = __builtin_amdgcn_mfma_f32_16x16x32_bf16(fqr[0],  bkp0, ph, 0,0,0);
      ph = __builtin_amdgcn_mfma_f32_16x16x32_bf16(fqr[1],  bkp1, ph, 0,0,0);
      ph = __builtin_amdgcn_mfma_f32_16x16x32_bf16(fqp[0],  bkr0, ph, 0,0,0);
      ph = __builtin_amdgcn_mfma_f32_16x16x32_bf16(fqp[1],  bkr1, ph, 0,0,0);
      sre[t] = re; sph[t] = ph;
    }

    // ---- magnitude + mask + online softmax (rows live in 16-lane groups) ----
    float pvals[4][4];
    float rmax[4];
    #pragma unroll
    for (int r = 0; r < 4; ++r) {
      rmax[r] = -1e30f;
      unsigned long long sh = mrow[r] >> lo;     // bit (16t) = col 16t+lo valid
      #pragma unroll
      for (int t = 0; t < 4; ++t) {
        float re = sre[t][r], ph = sph[t][r];
        float v = __builtin_amdgcn_sqrtf(re * re + ph * ph) * inv_scale;
        if (need_mask)
          v = ((unsigned int)(sh >> (16 * t)) & 1u) ? v : -1e9f;
        pvals[t][r] = v;
        rmax[r] = fmaxf(rmax[r], v);
      }
    }
    #pragma unroll
    for (int r = 0; r < 4; ++r) {
      float v = rmax[r];
      v = fmaxf(v, __shfl_xor(v, 1));
      v = fmaxf(v, __shfl_xor(v, 2));
      v = fmaxf(v, __shfl_xor(v, 4));
      v = fmaxf(v, __shfl_xor(v, 8));
      rmax[r] = v;
    }
    // exact defer-rescale: alpha==1 when tile max didn't grow the running max
    float alpha[4];
    bool grew = false;
    #pragma unroll
    for (int r = 0; r < 4; ++r) {
      float mold = m_run[r];
      float mnew = fmaxf(mold, rmax[r]);
      m_run[r] = mnew;
      bool g = (rmax[r] > mold);
      alpha[r] = g ? __expf(mold - mnew) : 1.0f;
      grew = grew || g;
    }
    #pragma unroll
    for (int r = 0; r < 4; ++r) {
      float rs = 0.f;
      #pragma unroll
      for (int t = 0; t < 4; ++t) {
        float p = __expf(pvals[t][r] - m_run[r]);
        pvals[t][r] = p;
        rs += p;
      }
      rs += __shfl_xor(rs, 1);
      rs += __shfl_xor(rs, 2);
      rs += __shfl_xor(rs, 4);
      rs += __shfl_xor(rs, 8);
      l_run[r] = l_run[r] * alpha[r] + rs;
    }
    if (__any((int)grew)) {
      #pragma unroll
      for (int r = 0; r < 4; ++r) {
        #pragma unroll
        for (int n = 0; n < 4; ++n) { o_r[n][r] *= alpha[r]; o_p[n][r] *= alpha[r]; }
      }
    }

    // ---- P -> bf16 -> LDS, XOR-swizzled (G4) ; wave-private, no barrier ----
    #pragma unroll
    for (int t = 0; t < 4; ++t) {
      #pragma unroll
      for (int r = 0; r < 4; ++r) {
        int row = 4 * hi + r;
        int off = row * 128 + ((((16 * t + lo) * 2) ^ ((row & 7) << 4)));
        *(unsigned short*)(pbase + off) = f2bf(pvals[t][r]);
      }
    }

    // ---- PV: A = P from LDS (row=q=lane&15, k'=8*hi+e), B = Vt rows ----
    short8 pa[2];
    #pragma unroll
    for (int hf = 0; hf < 2; ++hf) {
      int off = lo * 128 + (((hf * 64 + hi * 16)) ^ ((lo & 7) << 4));
      pa[hf] = *(const short8*)(pbase + off);
    }
    #pragma unroll
    for (int n = 0; n < 4; ++n) {
      const unsigned short* vr_row = Vr + (size_t)(16 * n + lo) * 2048 + k0;
      const unsigned short* vp_row = Vp + (size_t)(16 * n + lo) * 2048 + k0;
      short8 bvr0 = *(const short8*)(vr_row + 8 * hi);
      short8 bvr1 = *(const short8*)(vr_row + 32 + 8 * hi);
      short8 bvp0 = *(const short8*)(vp_row + 8 * hi);
      short8 bvp1 = *(const short8*)(vp_row + 32 + 8 * hi);
      o_r[n] = __builtin_amdgcn_mfma_f32_16x16x32_bf16(pa[0], bvr0, o_r[n], 0,0,0);
      o_r[n] = __builtin_amdgcn_mfma_f32_16x16x32_bf16(pa[1], bvr1, o_r[n], 0,0,0);
      o_p[n] = __builtin_amdgcn_mfma_f32_16x16x32_bf16(pa[0], bvp0, o_p[n], 0,0,0);
      o_p[n] = __builtin_amdgcn_mfma_f32_16x16x32_bf16(pa[1], bvp1, o_p[n], 0,0,0);
    }
  }

  // ---- epilogue: normalize, write xr/xp bf16 [B,S,D] ----
  float invl[4];
  #pragma unroll
  for (int r = 0; r < 4; ++r) invl[r] = 1.f / l_run[r];
  #pragma unroll
  for (int n = 0; n < 4; ++n) {
    #pragma unroll
    for (int r = 0; r < 4; ++r) {
      int q = q0 + 4 * hi + r;
      size_t off = (size_t)(b * Ss + q) * Dd + h * 64 + 16 * n + lo;
      xout[off]          = f2bf(o_r[n][r] * invl[r]);
      xout[MAT_E + off]  = f2bf(o_p[n][r] * invl[r]);
    }
  }
}

// ---------------- 4. output projection -> fp32 d_out ----------------
__global__ __launch_bounds__(256) void ck_out_gemm(
    const unsigned short* __restrict__ x,    // xr@0, xp@MAT_E bf16 [4096,512]
    const unsigned short* __restrict__ wot,  // w_o transposed bf16 [512,512]
    float* __restrict__ out)                 // z=0 -> first half, z=1 -> second
{
  int z = blockIdx.z;
  const unsigned short* A = x + (size_t)z * MAT_E;
  float* O = out + (size_t)z * MAT_E;

  int wave = threadIdx.x >> 6, lane = threadIdx.x & 63;
  int lo = lane & 15, hi = lane >> 4;
  int m0 = blockIdx.x * 64 + wave * 16;
  int n0 = blockIdx.y * 64;

  f32x4 acc[4];
  #pragma unroll
  for (int t = 0; t < 4; ++t) acc[t] = (f32x4){0.f, 0.f, 0.f, 0.f};

  for (int k0 = 0; k0 < 512; k0 += 32) {
    short8 a = *(const short8*)(A + (size_t)(m0 + lo) * 512 + k0 + 8 * hi);
    #pragma unroll
    for (int t = 0; t < 4; ++t) {
      short8 b = *(const short8*)(wot + (size_t)(n0 + 16 * t + lo) * 512 + k0 + 8 * hi);
      acc[t] = __builtin_amdgcn_mfma_f32_16x16x32_bf16(a, b, acc[t], 0, 0, 0);
    }
  }
  #pragma unroll
  for (int t = 0; t < 4; ++t) {
    #pragma unroll
    for (int r = 0; r < 4; ++r) {
      int m = m0 + 4 * hi + r;
      int n = n0 + 16 * t + lo;
      O[(size_t)m * 512 + n] = acc[t][r];
    }
  }
}

// ---------------- launch ----------------
extern "C" void kernel_launch(void* const* d_in, const int* in_sizes, int n_in,
                              void* d_out, int out_size, void* d_ws, size_t ws_size,
                              hipStream_t stream) {
  const float* q_real  = (const float*)d_in[0];
  const float* k_real  = (const float*)d_in[1];
  const float* v_real  = (const float*)d_in[2];
  const float* q_phase = (const float*)d_in[3];
  const float* k_phase = (const float*)d_in[4];
  const float* v_phase = (const float*)d_in[5];
  const float* w_q     = (const float*)d_in[6];
  const float* w_k     = (const float*)d_in[7];
  const float* w_v     = (const float*)d_in[8];
  const float* w_o     = (const float*)d_in[9];
  const int*   mask    = (const int*)d_in[10];
  float* out = (float*)d_out;

  unsigned short* ws   = (unsigned short*)d_ws;
  unsigned short* XB   = ws;                            // 6 * MAT_E bf16 (dead after proj)
  unsigned short* WT   = ws + 6 * (size_t)MAT_E;        // 4 * W_E
  unsigned short* PROJ = WT + 4 * (size_t)W_E;          // 6 * MAT_E
  unsigned short* XOUT = PROJ + 6 * (size_t)MAT_E;      // 2 * MAT_E
  unsigned long long* MB = (unsigned long long*)XB;     // 1 MB, aliases dead XB region

  ck_cvt_in  <<<dim3(2048, 6), 256, 0, stream>>>(q_real, k_real, v_real,
                                                 q_phase, k_phase, v_phase, XB);
  ck_cvt_wt  <<<dim3(1024, 4), 256, 0, stream>>>(w_q, w_k, w_v, w_o, WT);
  ck_proj_gemm<<<dim3(64, 8, 6), 256, 0, stream>>>(XB, WT, PROJ);
  ck_mask_pack<<<dim3(32768), 256, 0, stream>>>(mask, MB);   // after proj: XB is dead
  ck_attn    <<<dim3(512), 256, 0, stream>>>(PROJ, MB, XOUT);
  ck_out_gemm<<<dim3(64, 8, 2), 256, 0, stream>>>(XOUT, WT + 3 * (size_t)W_E, out);
}